// Round 1
// baseline (172.197 us; speedup 1.0000x reference)
//
#include <hip/hip_runtime.h>

#define HH 224
#define WW 224
#define PSD 112
#define NP 12544    // patches per plane (112*112)
#define NBG 1024    // B*G = 16*64

// ---------------------------------------------------------------------------
// Pass A: per-(b,g) 9x9 Gram matrix (upper triangle, 45) + column sums (9)
// ---------------------------------------------------------------------------
__global__ __launch_bounds__(256) void gram_k(const float* __restrict__ x,
                                              float* __restrict__ gram) {
    const int bg = blockIdx.x;
    const float* __restrict__ xp = x + (size_t)bg * (HH * WW);

    float acc[45];
    float sm[9];
#pragma unroll
    for (int k = 0; k < 45; ++k) acc[k] = 0.f;
#pragma unroll
    for (int i = 0; i < 9; ++i) sm[i] = 0.f;

    for (int p = threadIdx.x; p < NP; p += 256) {
        int ph = p / PSD;
        int pw = p - ph * PSD;
        int r0 = 2 * ph - 1;
        int c0 = 2 * pw - 1;
        float v[9];
#pragma unroll
        for (int kh = 0; kh < 3; ++kh) {
            int r = r0 + kh;
#pragma unroll
            for (int kw = 0; kw < 3; ++kw) {
                int cc = c0 + kw;
                float val = 0.f;
                if (r >= 0 && cc >= 0) val = xp[r * WW + cc];
                v[kh * 3 + kw] = val;
            }
        }
        int k = 0;
#pragma unroll
        for (int i = 0; i < 9; ++i) {
            sm[i] += v[i];
#pragma unroll
            for (int j = i; j < 9; ++j) {
                acc[k] += v[i] * v[j];
                ++k;
            }
        }
    }

    // block reduction: wave shuffle, then LDS across the 4 waves
    __shared__ float red[4][56];
    const int lane = threadIdx.x & 63;
    const int wv = threadIdx.x >> 6;
#pragma unroll
    for (int k = 0; k < 45; ++k) {
        float v = acc[k];
#pragma unroll
        for (int off = 32; off; off >>= 1) v += __shfl_down(v, off, 64);
        if (lane == 0) red[wv][k] = v;
    }
#pragma unroll
    for (int i = 0; i < 9; ++i) {
        float v = sm[i];
#pragma unroll
        for (int off = 32; off; off >>= 1) v += __shfl_down(v, off, 64);
        if (lane == 0) red[wv][45 + i] = v;
    }
    __syncthreads();
    if (threadIdx.x < 54) {
        float s = red[0][threadIdx.x] + red[1][threadIdx.x] +
                  red[2][threadIdx.x] + red[3][threadIdx.x];
        gram[bg * 64 + threadIdx.x] = s;
    }
}

// ---------------------------------------------------------------------------
// Pass B: per-(b,g) energy -> softmax -> effective 9-tap filter c[9] + bias d
// energy = Wk*M*Wq^T + bk*(Wq m)^T + (Wk m)*bq^T + P*bk*bq^T
// ---------------------------------------------------------------------------
__global__ __launch_bounds__(256) void attw_k(
    const float* __restrict__ Wq, const float* __restrict__ bq,
    const float* __restrict__ Wk, const float* __restrict__ bk,
    const float* __restrict__ Wv, const float* __restrict__ bv,
    const float* __restrict__ Wo, const float* __restrict__ bo,
    const float* __restrict__ gram, float* __restrict__ cd) {
    const int bg = blockIdx.x * 256 + threadIdx.x;
    if (bg >= NBG) return;
    const int g = bg & 63;

    const float* gp = gram + bg * 64;
    float M[9][9];
    {
        int k = 0;
#pragma unroll
        for (int i = 0; i < 9; ++i)
#pragma unroll
            for (int j = i; j < 9; ++j) {
                float v = gp[k++];
                M[i][j] = v;
                M[j][i] = v;
            }
    }
    float m[9];
#pragma unroll
    for (int i = 0; i < 9; ++i) m[i] = gp[45 + i];

    const float* wq = Wq + g * 81;
    const float* wk = Wk + g * 81;
    const float* bqg = bq + g * 9;
    const float* bkg = bk + g * 9;

    float Qm[9];
#pragma unroll
    for (int t = 0; t < 9; ++t) {
        float s = 0.f;
#pragma unroll
        for (int j = 0; j < 9; ++j) s += wq[t * 9 + j] * m[j];
        Qm[t] = s;
    }
    // T[i][t] = sum_j M[i][j] * Wq[t][j]
    float T[9][9];
#pragma unroll
    for (int i = 0; i < 9; ++i)
#pragma unroll
        for (int t = 0; t < 9; ++t) {
            float s = 0.f;
#pragma unroll
            for (int j = 0; j < 9; ++j) s += M[i][j] * wq[t * 9 + j];
            T[i][t] = s;
        }

    const float* wog = Wo + g * 9;
    float weff[9];
#pragma unroll
    for (int t = 0; t < 9; ++t) weff[t] = 0.f;

#pragma unroll
    for (int s = 0; s < 9; ++s) {
        float Km_s = 0.f;
#pragma unroll
        for (int i = 0; i < 9; ++i) Km_s += wk[s * 9 + i] * m[i];
        const float bks = bkg[s];
        float e[9];
#pragma unroll
        for (int t = 0; t < 9; ++t) {
            float sum = bks * Qm[t] + bqg[t] * Km_s + 12544.f * bks * bqg[t];
#pragma unroll
            for (int i = 0; i < 9; ++i) sum += wk[s * 9 + i] * T[i][t];
            e[t] = sum;
        }
        float mx = e[0];
#pragma unroll
        for (int t = 1; t < 9; ++t) mx = fmaxf(mx, e[t]);
        float ex[9], se = 0.f;
#pragma unroll
        for (int t = 0; t < 9; ++t) {
            ex[t] = expf(e[t] - mx);
            se += ex[t];
        }
        const float wos = wog[s] / se;
#pragma unroll
        for (int t = 0; t < 9; ++t) weff[t] += wos * ex[t];
    }

    const float* wv = Wv + g * 81;
    const float* bvg = bv + g * 9;
    float* o = cd + bg * 16;
    float d = bo[g];
#pragma unroll
    for (int j = 0; j < 9; ++j) {
        float s = 0.f;
#pragma unroll
        for (int t = 0; t < 9; ++t) s += weff[t] * wv[t * 9 + j];
        o[j] = s;
    }
#pragma unroll
    for (int t = 0; t < 9; ++t) d += weff[t] * bvg[t];
    o[9] = d;
}

// ---------------------------------------------------------------------------
// Pass C: out[b,g,ph,pw] = 3x3 stride-2 conv of x with per-(b,g) taps c + d
// ---------------------------------------------------------------------------
__global__ __launch_bounds__(256) void conv_k(const float* __restrict__ x,
                                              const float* __restrict__ cd,
                                              float* __restrict__ out) {
    const int bg = blockIdx.x;
    const float* __restrict__ xp = x + (size_t)bg * (HH * WW);
    const float* cp = cd + bg * 16;
    float c[9];
#pragma unroll
    for (int j = 0; j < 9; ++j) c[j] = cp[j];
    const float d = cp[9];
    float* op = out + (size_t)bg * NP;

    const int base = blockIdx.y * 16 * PSD;  // 1792 outputs per block
    for (int o = threadIdx.x; o < 16 * PSD; o += 256) {
        const int idx = base + o;
        int ph = idx / PSD;
        int pw = idx - ph * PSD;
        int r0 = 2 * ph - 1;
        int c0 = 2 * pw - 1;
        float s = d;
#pragma unroll
        for (int kh = 0; kh < 3; ++kh) {
            int r = r0 + kh;
#pragma unroll
            for (int kw = 0; kw < 3; ++kw) {
                int cc = c0 + kw;
                if (r >= 0 && cc >= 0) s += c[kh * 3 + kw] * xp[r * WW + cc];
            }
        }
        op[idx] = s;
    }
}

extern "C" void kernel_launch(void* const* d_in, const int* in_sizes, int n_in,
                              void* d_out, int out_size, void* d_ws, size_t ws_size,
                              hipStream_t stream) {
    const float* x = (const float*)d_in[0];
    const float* Wq = (const float*)d_in[1];
    const float* bq = (const float*)d_in[2];
    const float* Wk = (const float*)d_in[3];
    const float* bk = (const float*)d_in[4];
    const float* Wv = (const float*)d_in[5];
    const float* bv = (const float*)d_in[6];
    const float* Wo = (const float*)d_in[7];
    const float* bo = (const float*)d_in[8];
    float* out = (float*)d_out;

    float* gram = (float*)d_ws;          // NBG * 64 floats
    float* cd = gram + NBG * 64;         // NBG * 16 floats

    gram_k<<<NBG, 256, 0, stream>>>(x, gram);
    attw_k<<<4, 256, 0, stream>>>(Wq, bq, Wk, bk, Wv, bv, Wo, bo, gram, cd);
    conv_k<<<dim3(NBG, 7), 256, 0, stream>>>(x, cd, out);
}

// Round 2
// 78.539 us; speedup vs baseline: 2.1925x; 2.1925x over previous
//
#include <hip/hip_runtime.h>

#define HH 224
#define WW 224
#define PSD 112
#define NP 12544     // 112*112 patches per plane
#define NBG 1024     // B*G
#define NCH 28       // 4-patch chunks per patch row
#define NTASK (112 * NCH)  // 3136 tasks per plane

// upper-triangle index for symmetric 9x9: i<=j
#define MIDX(i, j) (9 * (i) - (i) * ((i)-1) / 2 + ((j) - (i)))
#define MAT(i, j) ((i) <= (j) ? sh[MIDX(i, j)] : sh[MIDX(j, i)])

// Load L[0..8] = x[r][8t-1 .. 8t+7] (r assumed >= 0)
__device__ __forceinline__ void load_row9(const float* __restrict__ row,
                                          int t, float* L) {
    const int cb = 8 * t;
    L[0] = (t == 0) ? 0.f : row[cb - 1];
    float4 a = *reinterpret_cast<const float4*>(row + cb);
    float4 b = *reinterpret_cast<const float4*>(row + cb + 4);
    L[1] = a.x; L[2] = a.y; L[3] = a.z; L[4] = a.w;
    L[5] = b.x; L[6] = b.y; L[7] = b.z; L[8] = b.w;
}

__global__ __launch_bounds__(256, 4) void scann_k(
    const float* __restrict__ x,
    const float* __restrict__ Wq, const float* __restrict__ bq,
    const float* __restrict__ Wk, const float* __restrict__ bk,
    const float* __restrict__ Wv, const float* __restrict__ bv,
    const float* __restrict__ Wo, const float* __restrict__ bo,
    float* __restrict__ out) {
    const int bg = blockIdx.x;
    const int g = bg & 63;
    const float* __restrict__ xp = x + (size_t)bg * (HH * WW);
    const int tid = threadIdx.x;

    __shared__ float red[4][56];
    __shared__ float sh[54];     // reduced gram: 45 upper + 9 sums
    __shared__ float TT[81];     // T[i][t]
    __shared__ float Qm_s[9];
    __shared__ float wsh[81];    // ws[s][t]
    __shared__ float cf[10];     // final 9 taps + bias

    // ---------------- Phase 1: gram accumulation ----------------
    float acc[45];
    float sm[9];
#pragma unroll
    for (int k = 0; k < 45; ++k) acc[k] = 0.f;
#pragma unroll
    for (int i = 0; i < 9; ++i) sm[i] = 0.f;

    for (int task = tid; task < NTASK; task += 256) {
        const int ph = task / NCH;
        const int t = task - ph * NCH;
        const int r0 = 2 * ph - 1;
        float L[3][9];
#pragma unroll
        for (int kr = 0; kr < 3; ++kr) {
            const int r = r0 + kr;
            if (r < 0) {
#pragma unroll
                for (int j = 0; j < 9; ++j) L[kr][j] = 0.f;
            } else {
                load_row9(xp + r * WW, t, L[kr]);
            }
        }
#pragma unroll
        for (int u = 0; u < 4; ++u) {
            float v[9];
#pragma unroll
            for (int kh = 0; kh < 3; ++kh)
#pragma unroll
                for (int kw = 0; kw < 3; ++kw) v[3 * kh + kw] = L[kh][2 * u + kw];
            int k = 0;
#pragma unroll
            for (int i = 0; i < 9; ++i) {
                sm[i] += v[i];
#pragma unroll
                for (int j = i; j < 9; ++j) {
                    acc[k] += v[i] * v[j];
                    ++k;
                }
            }
        }
    }

    // ---------------- Phase 2: block reduction ----------------
    {
        const int lane = tid & 63;
        const int wv = tid >> 6;
#pragma unroll
        for (int k = 0; k < 45; ++k) {
            float v = acc[k];
#pragma unroll
            for (int off = 32; off; off >>= 1) v += __shfl_down(v, off, 64);
            if (lane == 0) red[wv][k] = v;
        }
#pragma unroll
        for (int i = 0; i < 9; ++i) {
            float v = sm[i];
#pragma unroll
            for (int off = 32; off; off >>= 1) v += __shfl_down(v, off, 64);
            if (lane == 0) red[wv][45 + i] = v;
        }
    }
    __syncthreads();
    if (tid < 54)
        sh[tid] = red[0][tid] + red[1][tid] + red[2][tid] + red[3][tid];
    __syncthreads();

    // ---------------- Phase 3: attention weights (9 threads) ----------------
    // 3a: thread t computes Qm[t] and T[i][t] = sum_j M[i][j]*Wq[t][j]
    if (tid < 9) {
        const int t = tid;
        const float* wqt = Wq + g * 81 + t * 9;
        float w[9];
#pragma unroll
        for (int j = 0; j < 9; ++j) w[j] = wqt[j];
        float q = 0.f;
#pragma unroll
        for (int j = 0; j < 9; ++j) q += w[j] * sh[45 + j];
        Qm_s[t] = q;
#pragma unroll
        for (int i = 0; i < 9; ++i) {
            float s = 0.f;
#pragma unroll
            for (int j = 0; j < 9; ++j) s += MAT(i, j) * w[j];
            TT[i * 9 + t] = s;
        }
    }
    __syncthreads();
    // 3b: thread s computes row s of energy, softmax over t, ws[s][t]
    if (tid < 9) {
        const int s = tid;
        const float* wks = Wk + g * 81 + s * 9;
        float w[9];
#pragma unroll
        for (int i = 0; i < 9; ++i) w[i] = wks[i];
        float Km = 0.f;
#pragma unroll
        for (int i = 0; i < 9; ++i) Km += w[i] * sh[45 + i];
        const float bks = bk[g * 9 + s];
        float e[9];
#pragma unroll
        for (int t = 0; t < 9; ++t) {
            const float bqt = bq[g * 9 + t];
            float sum = bks * Qm_s[t] + bqt * Km + 12544.f * bks * bqt;
#pragma unroll
            for (int i = 0; i < 9; ++i) sum += w[i] * TT[i * 9 + t];
            e[t] = sum;
        }
        float mx = e[0];
#pragma unroll
        for (int t = 1; t < 9; ++t) mx = fmaxf(mx, e[t]);
        float ex[9], se = 0.f;
#pragma unroll
        for (int t = 0; t < 9; ++t) {
            ex[t] = expf(e[t] - mx);
            se += ex[t];
        }
        const float wos = Wo[g * 9 + s] / se;
#pragma unroll
        for (int t = 0; t < 9; ++t) wsh[s * 9 + t] = wos * ex[t];
    }
    __syncthreads();
    // 3c: thread j computes tap c[j]; thread 0 also bias d
    if (tid < 9) {
        const int j = tid;
        float weff[9];
#pragma unroll
        for (int t = 0; t < 9; ++t) {
            float s = 0.f;
#pragma unroll
            for (int s2 = 0; s2 < 9; ++s2) s += wsh[s2 * 9 + t];
            weff[t] = s;
        }
        float cj = 0.f;
#pragma unroll
        for (int t = 0; t < 9; ++t) cj += weff[t] * Wv[g * 81 + t * 9 + j];
        cf[j] = cj;
        if (j == 0) {
            float d = bo[g];
#pragma unroll
            for (int t = 0; t < 9; ++t) d += weff[t] * bv[g * 9 + t];
            cf[9] = d;
        }
    }
    __syncthreads();

    // ---------------- Phase 4: 3x3 stride-2 conv ----------------
    float cc[9];
#pragma unroll
    for (int j = 0; j < 9; ++j) cc[j] = cf[j];
    const float dd = cf[9];
    float* __restrict__ op = out + (size_t)bg * NP;

    for (int task = tid; task < NTASK; task += 256) {
        const int ph = task / NCH;
        const int t = task - ph * NCH;
        const int r0 = 2 * ph - 1;
        float L[3][9];
#pragma unroll
        for (int kr = 0; kr < 3; ++kr) {
            const int r = r0 + kr;
            if (r < 0) {
#pragma unroll
                for (int j = 0; j < 9; ++j) L[kr][j] = 0.f;
            } else {
                load_row9(xp + r * WW, t, L[kr]);
            }
        }
        float o[4];
#pragma unroll
        for (int u = 0; u < 4; ++u) {
            float s = dd;
#pragma unroll
            for (int kh = 0; kh < 3; ++kh)
#pragma unroll
                for (int kw = 0; kw < 3; ++kw)
                    s += cc[3 * kh + kw] * L[kh][2 * u + kw];
            o[u] = s;
        }
        *reinterpret_cast<float4*>(op + ph * PSD + 4 * t) =
            make_float4(o[0], o[1], o[2], o[3]);
    }
}

extern "C" void kernel_launch(void* const* d_in, const int* in_sizes, int n_in,
                              void* d_out, int out_size, void* d_ws, size_t ws_size,
                              hipStream_t stream) {
    const float* x = (const float*)d_in[0];
    const float* Wq = (const float*)d_in[1];
    const float* bq = (const float*)d_in[2];
    const float* Wk = (const float*)d_in[3];
    const float* bk = (const float*)d_in[4];
    const float* Wv = (const float*)d_in[5];
    const float* bv = (const float*)d_in[6];
    const float* Wo = (const float*)d_in[7];
    const float* bo = (const float*)d_in[8];
    float* out = (float*)d_out;

    scann_k<<<NBG, 256, 0, stream>>>(x, Wq, bq, Wk, bk, Wv, bv, Wo, bo, out);
}